// Round 14
// baseline (332.806 us; speedup 1.0000x reference)
//
#include <hip/hip_runtime.h>
#include <hip/hip_bf16.h>

// B=4, T=2048, C=1024, D=64 ; causal single-head attention, fp32 in/out.
// SINGLE fused persistent kernel: phase A (QKV projection for 16 rows) ->
// device-scope flag -> phase B (flash attention for the same 16 q-rows,
// consuming K/V tiles produced by same-batch blocks <= bid).
constexpr int Bn = 4;
constexpr int Tn = 2048;
constexpr int Cn = 1024;
constexpr int Dn = 64;
constexpr unsigned MAGIC = 0x5EEDF00Du;   // != 0xAAAAAAAA poison

typedef __attribute__((ext_vector_type(8))) short short8;  // 8 bf16
typedef __attribute__((ext_vector_type(4))) float f32x4;   // MFMA acc

__device__ inline short f2bf(float f) {
    unsigned u = __builtin_bit_cast(unsigned, f);
    u += 0x7FFFu + ((u >> 16) & 1u);
    return (short)(u >> 16);
}

// ---------------------------------------------------------------------------
// Grid: 512 blocks x 512 threads.  launch_bounds(512,4): 4 waves/SIMD min =>
// 2 blocks/CU x 256 CU = all 512 blocks co-resident (LDS 54.3KB x2 <= 160KB)
// => the inter-block flag wait cannot deadlock.
// Fragment convention (consistent A/B => k-permutation cancels):
//   A slot(lane,j)=A[lane&15][8*(lane>>4)+j], B slot=B[8*(lane>>4)+j][lane&15]
//   C/D (verified): row=(lane>>4)*4+reg, col=lane&15
// ---------------------------------------------------------------------------
__global__ __launch_bounds__(512, 4) void fused_attn(
    const float* __restrict__ x,
    const float* __restrict__ wq, const float* __restrict__ wk,
    const float* __restrict__ wv,
    const float* __restrict__ bq, const float* __restrict__ bk,
    const float* __restrict__ bv,
    short* __restrict__ Qbf, short* __restrict__ Kbf, short* __restrict__ Vt,
    unsigned* __restrict__ flags, float* __restrict__ out)
{
    __shared__ __align__(16) short Plds[8][16][72];
    __shared__ float o_part[8][16][68];
    __shared__ float ml_part[8][2][16];

    const int tid = threadIdx.x;
    const int w = tid >> 6, l = tid & 63;
    const int i = l & 15, g = l >> 4;
    const int bid = blockIdx.x;                   // 0..511
    const int rowbase = bid * 16;                 // global row (b*Tn + t)
    const int b = rowbase >> 11;                  // batch
    const int qw = rowbase & (Tn - 1);            // q-tile start within batch

    // ================= PHASE A: QKV projection (waves 0..5) =================
    if (w < 6) {
        const int sel = w >> 1, nh = w & 1;       // sel 0..2, col-half
        const float* wsrc = sel == 0 ? wq : (sel == 1 ? wk : wv);
        const float* bias = sel == 0 ? bq : (sel == 1 ? bk : bv);

        f32x4 acc[2];
        #pragma unroll
        for (int t2 = 0; t2 < 2; ++t2)
            #pragma unroll
            for (int r = 0; r < 4; ++r) acc[t2][r] = 0.f;

        const float* xrow = x + (size_t)(rowbase + i) * Cn + 8 * g;

        for (int k0 = 0; k0 < Cn; k0 += 32) {
            float4 x0 = *reinterpret_cast<const float4*>(xrow + k0);
            float4 x1 = *reinterpret_cast<const float4*>(xrow + k0 + 4);
            short8 af;
            af[0] = f2bf(x0.x); af[1] = f2bf(x0.y); af[2] = f2bf(x0.z); af[3] = f2bf(x0.w);
            af[4] = f2bf(x1.x); af[5] = f2bf(x1.y); af[6] = f2bf(x1.z); af[7] = f2bf(x1.w);
            #pragma unroll
            for (int t2 = 0; t2 < 2; ++t2) {
                const int n = nh * 32 + t2 * 16 + i;      // B col
                short8 bf;
                #pragma unroll
                for (int j = 0; j < 8; ++j)
                    bf[j] = f2bf(wsrc[(size_t)(k0 + 8 * g + j) * Dn + n]);
                acc[t2] = __builtin_amdgcn_mfma_f32_16x16x32_bf16(af, bf, acc[t2], 0, 0, 0);
            }
        }

        #pragma unroll
        for (int r = 0; r < 4; ++r) {
            const int rho = rowbase + 4 * g + r;          // C/D row (global)
            const int bb = rho >> 11, t = rho & (Tn - 1);
            #pragma unroll
            for (int t2 = 0; t2 < 2; ++t2) {
                const int n = nh * 32 + t2 * 16 + i;      // C/D col
                const float val = acc[t2][r] + bias[n];
                if (sel == 0)      Qbf[(size_t)rho * Dn + n] = f2bf(val * 0.125f);
                else if (sel == 1) Kbf[(size_t)rho * Dn + n] = f2bf(val);
                else               Vt[((size_t)bb * Dn + n) * Tn + t] = f2bf(val);
            }
        }
    }

    // release: all stores visible device-wide, then publish flag
    __threadfence();
    __syncthreads();
    if (tid == 0) atomicExch(&flags[bid], MAGIC);

    // acquire: wait for same-batch producer blocks [b*128 .. bid]
    if (w == 0) {
        for (int j = b * 128 + l; j <= bid; j += 64)
            while (atomicAdd(&flags[j], 0u) != MAGIC)
                __builtin_amdgcn_s_sleep(32);
    }
    __syncthreads();
    __threadfence();

    // ================= PHASE B: flash attention (all 8 waves) ===============
    const short* Qb = Qbf + (size_t)b * Tn * Dn;
    const short* Kb = Kbf + (size_t)b * Tn * Dn;
    const short* Vb = Vt + (size_t)b * Dn * Tn;

    short8 qf0 = *reinterpret_cast<const short8*>(Qb + (size_t)(qw + i) * Dn + 8 * g);
    short8 qf1 = *reinterpret_cast<const short8*>(Qb + (size_t)(qw + i) * Dn + 32 + 8 * g);

    f32x4 o4[4];
    f32x4 m, lsum;
    #pragma unroll
    for (int r = 0; r < 4; ++r) { m[r] = -1e30f; lsum[r] = 0.f; }
    #pragma unroll
    for (int dt = 0; dt < 4; ++dt)
        #pragma unroll
        for (int r = 0; r < 4; ++r) o4[dt][r] = 0.f;

    const int nch = (qw + 79) >> 6;               // 64-key chunks
    for (int kb = w; kb < nch; kb += 8) {
        const int K0 = kb * 64;

        // ---- S = Q K^T ----
        f32x4 s[4];
        #pragma unroll
        for (int nt = 0; nt < 4; ++nt)
            #pragma unroll
            for (int r = 0; r < 4; ++r) s[nt][r] = 0.f;
        #pragma unroll
        for (int nt = 0; nt < 4; ++nt) {
            const short* kr = Kb + (size_t)(K0 + nt * 16 + i) * Dn + 8 * g;
            short8 kf0 = *reinterpret_cast<const short8*>(kr);
            short8 kf1 = *reinterpret_cast<const short8*>(kr + 32);
            s[nt] = __builtin_amdgcn_mfma_f32_16x16x32_bf16(qf0, kf0, s[nt], 0, 0, 0);
            s[nt] = __builtin_amdgcn_mfma_f32_16x16x32_bf16(qf1, kf1, s[nt], 0, 0, 0);
        }

        // ---- causal mask ----
        if (K0 + 63 > qw) {
            #pragma unroll
            for (int nt = 0; nt < 4; ++nt)
                #pragma unroll
                for (int r = 0; r < 4; ++r)
                    if (K0 + nt * 16 + i > qw + 4 * g + r) s[nt][r] = -1e30f;
        }

        // ---- online softmax ----
        f32x4 rm;
        #pragma unroll
        for (int r = 0; r < 4; ++r)
            rm[r] = fmaxf(fmaxf(s[0][r], s[1][r]), fmaxf(s[2][r], s[3][r]));
        #pragma unroll
        for (int msk = 1; msk < 16; msk <<= 1)
            #pragma unroll
            for (int r = 0; r < 4; ++r) rm[r] = fmaxf(rm[r], __shfl_xor(rm[r], msk));

        f32x4 scl;
        #pragma unroll
        for (int r = 0; r < 4; ++r) {
            float mn = fmaxf(m[r], rm[r]);
            scl[r] = __expf(m[r] - mn);
            m[r] = mn;
            lsum[r] *= scl[r];
        }
        #pragma unroll
        for (int dt = 0; dt < 4; ++dt)
            #pragma unroll
            for (int r = 0; r < 4; ++r) o4[dt][r] *= scl[r];

        f32x4 rs;
        #pragma unroll
        for (int r = 0; r < 4; ++r) rs[r] = 0.f;
        #pragma unroll
        for (int nt = 0; nt < 4; ++nt)
            #pragma unroll
            for (int r = 0; r < 4; ++r) {
                float p = __expf(s[nt][r] - m[r]);
                rs[r] += p;
                Plds[w][4 * g + r][nt * 16 + i] = f2bf(p);
            }
        #pragma unroll
        for (int msk = 1; msk < 16; msk <<= 1)
            #pragma unroll
            for (int r = 0; r < 4; ++r) rs[r] += __shfl_xor(rs[r], msk);
        #pragma unroll
        for (int r = 0; r < 4; ++r) lsum[r] += rs[r];

        asm volatile("s_waitcnt lgkmcnt(0)" ::: "memory");
        __builtin_amdgcn_sched_barrier(0);

        // ---- O += P V ----
        short8 pf0 = *reinterpret_cast<const short8*>(&Plds[w][i][8 * g]);
        short8 pf1 = *reinterpret_cast<const short8*>(&Plds[w][i][32 + 8 * g]);
        #pragma unroll
        for (int dt = 0; dt < 4; ++dt) {
            const short* vr = Vb + (size_t)(dt * 16 + i) * Tn + K0 + 8 * g;
            short8 vf0 = *reinterpret_cast<const short8*>(vr);
            short8 vf1 = *reinterpret_cast<const short8*>(vr + 32);
            o4[dt] = __builtin_amdgcn_mfma_f32_16x16x32_bf16(pf0, vf0, o4[dt], 0, 0, 0);
            o4[dt] = __builtin_amdgcn_mfma_f32_16x16x32_bf16(pf1, vf1, o4[dt], 0, 0, 0);
        }
    }

    // ---- publish partials ----
    #pragma unroll
    for (int dt = 0; dt < 4; ++dt)
        #pragma unroll
        for (int r = 0; r < 4; ++r)
            o_part[w][4 * g + r][dt * 16 + i] = o4[dt][r];
    if (i == 0) {
        #pragma unroll
        for (int r = 0; r < 4; ++r) {
            ml_part[w][0][4 * g + r] = m[r];
            ml_part[w][1][4 * g + r] = lsum[r];
        }
    }
    __syncthreads();

    // ---- merge: waves 0-3 own output cols [16w, 16w+16) ----
    if (w < 4) {
        #pragma unroll
        for (int r = 0; r < 4; ++r) {
            const int row = 4 * g + r;
            float M = -1e30f;
            #pragma unroll
            for (int p = 0; p < 8; ++p) M = fmaxf(M, ml_part[p][0][row]);
            float L = 0.f, O = 0.f;
            #pragma unroll
            for (int p = 0; p < 8; ++p) {
                float wp = __expf(ml_part[p][0][row] - M);
                L += ml_part[p][1][row] * wp;
                O += o_part[p][row][w * 16 + i] * wp;
            }
            out[((size_t)b * Tn + qw + row) * Dn + w * 16 + i] = O / L;
        }
    }
}

// ---------------------------------------------------------------------------
extern "C" void kernel_launch(void* const* d_in, const int* in_sizes, int n_in,
                              void* d_out, int out_size, void* d_ws, size_t ws_size,
                              hipStream_t stream) {
    const float* x  = (const float*)d_in[0];
    const float* wq = (const float*)d_in[1];
    const float* wk = (const float*)d_in[2];
    const float* wv = (const float*)d_in[3];
    const float* bq = (const float*)d_in[4];
    const float* bk = (const float*)d_in[5];
    const float* bv = (const float*)d_in[6];
    float* out = (float*)d_out;

    short* Qbf = (short*)d_ws;                        // 4*2048*64 bf16 each
    short* Kbf = Qbf + (size_t)Bn * Tn * Dn;
    short* Vt  = Kbf + (size_t)Bn * Tn * Dn;          // transposed (b,d,t)
    unsigned* flags = (unsigned*)(Vt + (size_t)Bn * Tn * Dn);  // 512 words

    fused_attn<<<512, 512, 0, stream>>>(
        x, wq, wk, wv, bq, bk, bv, Qbf, Kbf, Vt, flags, out);
}

// Round 15
// 147.602 us; speedup vs baseline: 2.2548x; 2.2548x over previous
//
#include <hip/hip_runtime.h>
#include <hip/hip_bf16.h>

// B=4, T=2048, C=1024, D=64 ; causal single-head attention, fp32 in/out.
constexpr int Bn = 4;
constexpr int Tn = 2048;
constexpr int Cn = 1024;
constexpr int Dn = 64;

typedef __attribute__((ext_vector_type(8))) short short8;  // 8 bf16 (4 VGPRs)
typedef __attribute__((ext_vector_type(4))) float f32x4;   // MFMA acc

// fp32 -> bf16 bits, round-to-nearest-even
__device__ inline short f2bf(float f) {
    unsigned u = __builtin_bit_cast(unsigned, f);
    u += 0x7FFFu + ((u >> 16) & 1u);
    return (short)(u >> 16);
}

// ---------------------------------------------------------------------------
// Kernel 0: weights -> bf16, transposed: wt[sel][n=0..63][k=0..1023]
// ---------------------------------------------------------------------------
__global__ __launch_bounds__(256) void prep_w(
    const float* __restrict__ wq, const float* __restrict__ wk,
    const float* __restrict__ wv, short* __restrict__ wt)
{
    const int sel = blockIdx.x >> 4;           // 48 blocks: 3 sel x 16 parts
    const float* w = sel == 0 ? wq : (sel == 1 ? wk : wv);
    short* o = wt + (size_t)sel * Dn * Cn;
    const int base = (blockIdx.x & 15) * 4096;
    for (int idx = base + threadIdx.x; idx < base + 4096; idx += 256) {
        int n = idx >> 10, k = idx & 1023;     // write o[n][k] coalesced
        o[idx] = f2bf(w[k * Dn + n]);
    }
}

// ---------------------------------------------------------------------------
// Kernel 1: QKV projection via bf16 MFMA (r12 structure, measured-equal best).
// Grid (512,3): y=sel, one wave/block, 16 rows x 64 cols, depth-2 x-prefetch.
// Fragment convention (consistent A/B => k-permutation cancels):
//   A slot(lane,j)=A[lane&15][8*(lane>>4)+j], B slot=B[8*(lane>>4)+j][lane&15]
//   C/D (verified): row=(lane>>4)*4+reg, col=lane&15
// ---------------------------------------------------------------------------
__global__ __launch_bounds__(64) void qkv_mfma(
    const float* __restrict__ x, const short* __restrict__ wt,
    const float* __restrict__ bq, const float* __restrict__ bk,
    const float* __restrict__ bv,
    short* __restrict__ Qbf, short* __restrict__ Kbf, short* __restrict__ Vt)
{
    const int l = threadIdx.x;
    const int i = l & 15, g = l >> 4;
    const int rowbase = blockIdx.x * 16;
    const int sel = blockIdx.y;

    const short* ws   = wt + (size_t)sel * Dn * Cn;
    const float* bias = sel == 0 ? bq : (sel == 1 ? bk : bv);

    f32x4 acc[4];
    #pragma unroll
    for (int nt = 0; nt < 4; ++nt)
        #pragma unroll
        for (int r = 0; r < 4; ++r) acc[nt][r] = 0.f;

    const float* xrow = x + (size_t)(rowbase + i) * Cn + 8 * g;

    float4 pa[2], pb[2];
    pa[0] = *reinterpret_cast<const float4*>(xrow + 0);
    pb[0] = *reinterpret_cast<const float4*>(xrow + 4);
    pa[1] = *reinterpret_cast<const float4*>(xrow + 32);
    pb[1] = *reinterpret_cast<const float4*>(xrow + 36);

    #pragma unroll
    for (int k0 = 0; k0 < Cn; k0 += 32) {
        const int s = (k0 >> 5) & 1;
        float4 x0 = pa[s], x1 = pb[s];
        const int kn = k0 + 64;
        if (kn < Cn) {
            pa[s] = *reinterpret_cast<const float4*>(xrow + kn);
            pb[s] = *reinterpret_cast<const float4*>(xrow + kn + 4);
        }
        short8 af;
        af[0] = f2bf(x0.x); af[1] = f2bf(x0.y); af[2] = f2bf(x0.z); af[3] = f2bf(x0.w);
        af[4] = f2bf(x1.x); af[5] = f2bf(x1.y); af[6] = f2bf(x1.z); af[7] = f2bf(x1.w);
        #pragma unroll
        for (int nt = 0; nt < 4; ++nt) {
            short8 bf = *reinterpret_cast<const short8*>(
                ws + (size_t)(nt * 16 + i) * Cn + k0 + 8 * g);
            acc[nt] = __builtin_amdgcn_mfma_f32_16x16x32_bf16(af, bf, acc[nt], 0, 0, 0);
        }
    }

    #pragma unroll
    for (int r = 0; r < 4; ++r) {
        const int rho = rowbase + 4 * g + r;
        const int b = rho >> 11, t = rho & (Tn - 1);
        #pragma unroll
        for (int nt = 0; nt < 4; ++nt) {
            const int n = nt * 16 + i;
            const float val = acc[nt][r] + bias[n];
            if (sel == 0)      Qbf[(size_t)rho * Dn + n] = f2bf(val * 0.125f);
            else if (sel == 1) Kbf[(size_t)rho * Dn + n] = f2bf(val);
            else               Vt[((size_t)b * Dn + n) * Tn + t] = f2bf(val);
        }
    }
}

// ---------------------------------------------------------------------------
// Kernel 2: fused causal flash attention, 8-wave KV-split + V-hoist +
// SWAPPED QK^T (T12): s = mfma(K, Q) so D col = q-row = lane&15 and each
// lane holds 16 keys of ONE q-row.  Softmax row-reduce becomes in-lane
// (15 fmax / 16 add) + 2 shfl_xor rounds; m/lsum are per-lane scalars.
// Cross-lane ops per chunk: 40 -> 8.  P relayout via LDS as before.
// ---------------------------------------------------------------------------
__global__ __launch_bounds__(512) void attn_fused(
    const short* __restrict__ Qbf, const short* __restrict__ Kbf,
    const short* __restrict__ Vt, float* __restrict__ out)
{
    __shared__ __align__(16) short Plds[8][16][72];
    __shared__ float o_part[8][16][68];
    __shared__ float ml_part[8][2][16];

    const int tid = threadIdx.x;
    const int w = tid >> 6, l = tid & 63;
    const int i = l & 15, g = l >> 4;
    const int b = blockIdx.y;
    const int qw = blockIdx.x * 16;

    const short* Qb = Qbf + (size_t)b * Tn * Dn;
    const short* Kb = Kbf + (size_t)b * Tn * Dn;
    const short* Vb = Vt + (size_t)b * Dn * Tn;

    short8 qf0 = *reinterpret_cast<const short8*>(Qb + (size_t)(qw + i) * Dn + 8 * g);
    short8 qf1 = *reinterpret_cast<const short8*>(Qb + (size_t)(qw + i) * Dn + 32 + 8 * g);

    f32x4 o4[4];
    float m = -1e30f, lsum = 0.f;          // per-lane scalars: q-row = i
    #pragma unroll
    for (int dt = 0; dt < 4; ++dt)
        #pragma unroll
        for (int r = 0; r < 4; ++r) o4[dt][r] = 0.f;

    const int nch = (qw + 79) >> 6;
    for (int kb = w; kb < nch; kb += 8) {
        const int K0 = kb * 64;

        // ---- S^T = K Q^T : D[row=key(4g+r), col=q(i)] ----
        f32x4 s[4];
        #pragma unroll
        for (int nt = 0; nt < 4; ++nt)
            #pragma unroll
            for (int r = 0; r < 4; ++r) s[nt][r] = 0.f;
        #pragma unroll
        for (int nt = 0; nt < 4; ++nt) {
            const short* kr = Kb + (size_t)(K0 + nt * 16 + i) * Dn + 8 * g;
            short8 kf0 = *reinterpret_cast<const short8*>(kr);
            short8 kf1 = *reinterpret_cast<const short8*>(kr + 32);
            s[nt] = __builtin_amdgcn_mfma_f32_16x16x32_bf16(kf0, qf0, s[nt], 0, 0, 0);
            s[nt] = __builtin_amdgcn_mfma_f32_16x16x32_bf16(kf1, qf1, s[nt], 0, 0, 0);
        }

        // ---- V-load hoist: issue now, consume after softmax ----
        short8 vf0[4], vf1[4];
        #pragma unroll
        for (int dt = 0; dt < 4; ++dt) {
            const short* vr = Vb + (size_t)(dt * 16 + i) * Tn + K0 + 8 * g;
            vf0[dt] = *reinterpret_cast<const short8*>(vr);
            vf1[dt] = *reinterpret_cast<const short8*>(vr + 32);
        }

        // ---- causal mask: key = K0+nt*16+4g+r, q = qw+i ----
        if (K0 + 63 > qw) {
            #pragma unroll
            for (int nt = 0; nt < 4; ++nt)
                #pragma unroll
                for (int r = 0; r < 4; ++r)
                    if (K0 + nt * 16 + 4 * g + r > qw + i) s[nt][r] = -1e30f;
        }

        // ---- online softmax (in-lane over 16 keys + 2 shfl rounds) ----
        float rm = s[0][0];
        #pragma unroll
        for (int nt = 0; nt < 4; ++nt)
            #pragma unroll
            for (int r = 0; r < 4; ++r) rm = fmaxf(rm, s[nt][r]);
        rm = fmaxf(rm, __shfl_xor(rm, 16));
        rm = fmaxf(rm, __shfl_xor(rm, 32));

        const float mn = fmaxf(m, rm);
        const float scl = __expf(m - mn);
        m = mn;
        lsum *= scl;

        // broadcast scl into o4's row layout (q = 4g+r lives at lane 4g+r)
        float sclq[4];
        #pragma unroll
        for (int r = 0; r < 4; ++r) sclq[r] = __shfl(scl, 4 * g + r);
        #pragma unroll
        for (int dt = 0; dt < 4; ++dt)
            #pragma unroll
            for (int r = 0; r < 4; ++r) o4[dt][r] *= sclq[r];

        // ---- P = exp(S-m), row sums in-lane, spill to LDS[q][key] ----
        float rs = 0.f;
        #pragma unroll
        for (int nt = 0; nt < 4; ++nt)
            #pragma unroll
            for (int r = 0; r < 4; ++r) {
                float p = __expf(s[nt][r] - m);
                rs += p;
                Plds[w][i][nt * 16 + 4 * g + r] = f2bf(p);
            }
        rs += __shfl_xor(rs, 16);
        rs += __shfl_xor(rs, 32);
        lsum += rs;

        // wave-private LDS roundtrip: drain own writes, pin ordering
        asm volatile("s_waitcnt lgkmcnt(0)" ::: "memory");
        __builtin_amdgcn_sched_barrier(0);

        // ---- O += P V (A-frag rows = q = lane&15, as before) ----
        short8 pf0 = *reinterpret_cast<const short8*>(&Plds[w][i][8 * g]);
        short8 pf1 = *reinterpret_cast<const short8*>(&Plds[w][i][32 + 8 * g]);
        #pragma unroll
        for (int dt = 0; dt < 4; ++dt) {
            o4[dt] = __builtin_amdgcn_mfma_f32_16x16x32_bf16(pf0, vf0[dt], o4[dt], 0, 0, 0);
            o4[dt] = __builtin_amdgcn_mfma_f32_16x16x32_bf16(pf1, vf1[dt], o4[dt], 0, 0, 0);
        }
    }

    // ---- publish partials (o4 layout unchanged: row q=4g+r, col d) ----
    #pragma unroll
    for (int dt = 0; dt < 4; ++dt)
        #pragma unroll
        for (int r = 0; r < 4; ++r)
            o_part[w][4 * g + r][dt * 16 + i] = o4[dt][r];
    if (g == 0) {                          // lanes 0..15: q-row = i
        ml_part[w][0][i] = m;
        ml_part[w][1][i] = lsum;
    }
    __syncthreads();

    // ---- merge: waves 0-3 own output cols [16w, 16w+16) ----
    if (w < 4) {
        #pragma unroll
        for (int r = 0; r < 4; ++r) {
            const int row = 4 * g + r;
            float M = -1e30f;
            #pragma unroll
            for (int p = 0; p < 8; ++p) M = fmaxf(M, ml_part[p][0][row]);
            float L = 0.f, O = 0.f;
            #pragma unroll
            for (int p = 0; p < 8; ++p) {
                float wp = __expf(ml_part[p][0][row] - M);
                L += ml_part[p][1][row] * wp;
                O += o_part[p][row][w * 16 + i] * wp;
            }
            out[((size_t)b * Tn + qw + row) * Dn + w * 16 + i] = O / L;
        }
    }
}

// ---------------------------------------------------------------------------
extern "C" void kernel_launch(void* const* d_in, const int* in_sizes, int n_in,
                              void* d_out, int out_size, void* d_ws, size_t ws_size,
                              hipStream_t stream) {
    const float* x  = (const float*)d_in[0];
    const float* wq = (const float*)d_in[1];
    const float* wk = (const float*)d_in[2];
    const float* wv = (const float*)d_in[3];
    const float* bq = (const float*)d_in[4];
    const float* bk = (const float*)d_in[5];
    const float* bv = (const float*)d_in[6];
    float* out = (float*)d_out;

    short* wt  = (short*)d_ws;                       // 3*64*1024  bf16
    short* Qbf = wt + 3 * Dn * Cn;                   // 4*2048*64  bf16 each
    short* Kbf = Qbf + (size_t)Bn * Tn * Dn;
    short* Vt  = Kbf + (size_t)Bn * Tn * Dn;         // transposed (b,d,t)

    prep_w<<<48, 256, 0, stream>>>(wq, wk, wv, wt);
    qkv_mfma<<<dim3((Bn * Tn) / 16, 3), 64, 0, stream>>>(
        x, wt, bq, bk, bv, Qbf, Kbf, Vt);
    attn_fused<<<dim3(Tn / 16, Bn), 512, 0, stream>>>(Qbf, Kbf, Vt, out);
}